// Round 16
// baseline (1083.212 us; speedup 1.0000x reference)
//
#include <hip/hip_runtime.h>
#include <math.h>
#include <float.h>

#define BM 128
#define BN 128
#define BK 16
#define TM 8
#define TN 8
#define LDA_S (BM + 4)      // 132
#define LDB_S (BN + 16)     // 144

__device__ __forceinline__ int bpad(int c) { return c + ((c >> 5) << 2); }

// C = leaky_relu(A[M,K] @ W[K,N] + bias[N]), fp32, row-major.
// Double-buffered LDS, ONE barrier per K-tile. Accumulation order (k
// ascending per output elem) identical to the R13-verified kernel ->
// bit-identical output.
__global__ __launch_bounds__(256) void sgemm_bias_act(
    const float* __restrict__ A, const float* __restrict__ W,
    const float* __restrict__ bias, float* __restrict__ C,
    int M, int K, int N)
{
    __shared__ float As[2][BK * LDA_S];
    __shared__ float Bs[2][BK * LDB_S];

    const int tid = threadIdx.x;
    const int bm = blockIdx.x;
    const int bn = blockIdx.y;

    const int tn = tid & 15;
    const int tm = tid >> 4;
    const int row0 = tm * TM;
    const int col0 = tn * TN;
    const int cs0 = bpad(col0);

    const int lr  = tid >> 2;          // 0..63
    const int lc4 = (tid & 3) << 2;    // 0,4,8,12
    const int br  = tid >> 5;          // 0..7
    const int bc4 = (tid & 31) << 2;   // 0..124
    const int bcs = bpad(bc4);

    const float* Ag = A + (size_t)(bm * BM) * K;
    const float* Wg = W + (size_t)bn * BN;

    float acc[TM][TN];
#pragma unroll
    for (int i = 0; i < TM; ++i)
#pragma unroll
        for (int j = 0; j < TN; ++j) acc[i][j] = 0.f;

    float4 a0, a1, b0, b1;
#define LOAD_TILE(k0_)                                                        \
    do {                                                                      \
        a0 = *(const float4*)(Ag + (size_t)lr * K + (k0_) + lc4);             \
        a1 = *(const float4*)(Ag + (size_t)(lr + 64) * K + (k0_) + lc4);      \
        b0 = *(const float4*)(Wg + (size_t)((k0_) + br) * N + bc4);           \
        b1 = *(const float4*)(Wg + (size_t)((k0_) + br + 8) * N + bc4);       \
    } while (0)

#define STORE_TILE(buf_)                                                      \
    do {                                                                      \
        As[buf_][(lc4 + 0) * LDA_S + lr] = a0.x;                              \
        As[buf_][(lc4 + 1) * LDA_S + lr] = a0.y;                              \
        As[buf_][(lc4 + 2) * LDA_S + lr] = a0.z;                              \
        As[buf_][(lc4 + 3) * LDA_S + lr] = a0.w;                              \
        As[buf_][(lc4 + 0) * LDA_S + lr + 64] = a1.x;                         \
        As[buf_][(lc4 + 1) * LDA_S + lr + 64] = a1.y;                         \
        As[buf_][(lc4 + 2) * LDA_S + lr + 64] = a1.z;                         \
        As[buf_][(lc4 + 3) * LDA_S + lr + 64] = a1.w;                         \
        *(float4*)&Bs[buf_][br * LDB_S + bcs] = b0;                           \
        *(float4*)&Bs[buf_][(br + 8) * LDB_S + bcs] = b1;                     \
    } while (0)

    // prologue: tile 0 -> buf0; issue tile-1 loads; barrier
    LOAD_TILE(0);
    STORE_TILE(0);
    if (BK < K) LOAD_TILE(BK);
    __syncthreads();

    int cur = 0;
    for (int k0 = 0; k0 < K; k0 += BK) {
        // (a) store tile t+1 (in regs) into the other buffer
        if (k0 + BK < K) STORE_TILE(cur ^ 1);
        // (b) issue global loads for tile t+2
        if (k0 + 2 * BK < K) LOAD_TILE(k0 + 2 * BK);
        // (c) compute tile t from buf[cur] — pure FMA on float4 components
        const float* Ac = As[cur];
        const float* Bc = Bs[cur];
#pragma unroll
        for (int kk = 0; kk < BK; ++kk) {
            const float4 av0 = *(const float4*)&Ac[kk * LDA_S + row0];
            const float4 av1 = *(const float4*)&Ac[kk * LDA_S + row0 + 4];
            const float4 bv0 = *(const float4*)&Bc[kk * LDB_S + cs0];
            const float4 bv1 = *(const float4*)&Bc[kk * LDB_S + cs0 + 4];
#define FMA_ROW(i, ax)                                                        \
            acc[i][0] = fmaf(ax, bv0.x, acc[i][0]);                           \
            acc[i][1] = fmaf(ax, bv0.y, acc[i][1]);                           \
            acc[i][2] = fmaf(ax, bv0.z, acc[i][2]);                           \
            acc[i][3] = fmaf(ax, bv0.w, acc[i][3]);                           \
            acc[i][4] = fmaf(ax, bv1.x, acc[i][4]);                           \
            acc[i][5] = fmaf(ax, bv1.y, acc[i][5]);                           \
            acc[i][6] = fmaf(ax, bv1.z, acc[i][6]);                           \
            acc[i][7] = fmaf(ax, bv1.w, acc[i][7])
            FMA_ROW(0, av0.x); FMA_ROW(1, av0.y);
            FMA_ROW(2, av0.z); FMA_ROW(3, av0.w);
            FMA_ROW(4, av1.x); FMA_ROW(5, av1.y);
            FMA_ROW(6, av1.z); FMA_ROW(7, av1.w);
#undef FMA_ROW
        }
        __syncthreads();   // single barrier: orders (c)-reads and (a)-writes
        cur ^= 1;
    }

    // epilogue: bias + leaky_relu(0.01)
    float bv[TN];
#pragma unroll
    for (int j = 0; j < TN; ++j) bv[j] = bias[bn * BN + col0 + j];
#pragma unroll
    for (int i = 0; i < TM; ++i) {
        float o[TN];
#pragma unroll
        for (int j = 0; j < TN; ++j) {
            float x = acc[i][j] + bv[j];
            o[j] = x > 0.f ? x : 0.01f * x;
        }
        float* Cp = C + (size_t)(bm * BM + row0 + i) * N + (size_t)bn * BN + col0;
        *(float4*)Cp       = make_float4(o[0], o[1], o[2], o[3]);
        *(float4*)(Cp + 4) = make_float4(o[4], o[5], o[6], o[7]);
    }
#undef LOAD_TILE
#undef STORE_TILE
}

// s[row] = h[row,:] . Wout + bout   (one wave per row; verified R9/R13)
__global__ __launch_bounds__(256) void gemv_wout(
    const float* __restrict__ H, const float* __restrict__ Wout,
    const float* __restrict__ bout, float* __restrict__ s, int K)
{
    const int row  = blockIdx.x * 4 + (threadIdx.x >> 6);
    const int lane = threadIdx.x & 63;
    const float4* h = (const float4*)(H + (size_t)row * K);
    const float4* w = (const float4*)Wout;
    float acc = 0.f;
    const int nv = K >> 2;
#pragma unroll
    for (int t = lane; t < nv; t += 64) {
        float4 hv = h[t];
        float4 wv = w[t];
        acc += hv.x * wv.x + hv.y * wv.y + hv.z * wv.z + hv.w * wv.w;
    }
#pragma unroll
    for (int off = 32; off; off >>= 1) acc += __shfl_xor(acc, off);
    if (lane == 0) s[row] = acc + bout[0];
}

// ---------------- parallel prefix-top-k (verified R13) ----------------------
#define EMPTY_SENTINEL (-1.0e38f)
#define HEAP_SENTINEL  (-1e30f)

__global__ void chunk_sort(const float* __restrict__ s,
                           float* __restrict__ cval, int* __restrict__ cidx)
{
    const int lane = threadIdx.x;
    const int base = blockIdx.x * 64;
    float v  = s[base + lane];
    int   id = base + lane;
#pragma unroll
    for (int ksz = 2; ksz <= 64; ksz <<= 1) {
#pragma unroll
        for (int j = 32; j >= 1; j >>= 1) {
            if (j >= ksz) continue;
            float ov = __shfl_xor(v, j);
            int   oi = __shfl_xor(id, j);
            const bool lower    = ((lane & j) == 0);
            const bool dirDesc  = ((lane & ksz) == 0);
            const bool wantBig  = (lower == dirDesc);
            const bool mineBig  = (v > ov) || (v == ov && id < oi);
            const bool keepMine = (mineBig == wantBig);
            v  = keepMine ? v  : ov;
            id = keepMine ? id : oi;
        }
    }
    cval[base + lane] = v;
    cidx[base + lane] = id;
}

__global__ void prefix_merge(const float* __restrict__ cval,
                             const int* __restrict__ cidx,
                             float* __restrict__ qval, int* __restrict__ qidx,
                             int nchunks)
{
    const int lane = threadIdx.x;
    float v  = HEAP_SENTINEL;
    int   id = 0x3FFFFFFF;
    for (int c = 0; c < nchunks; ++c) {
        qval[c * 64 + lane] = v;
        qidx[c * 64 + lane] = id;
        float bv = cval[c * 64 + (63 - lane)];
        int   bi = cidx[c * 64 + (63 - lane)];
        const bool mineBig0 = (v > bv) || (v == bv && id < bi);
        v  = mineBig0 ? v  : bv;
        id = mineBig0 ? id : bi;
#pragma unroll
        for (int j = 32; j >= 1; j >>= 1) {
            float ov = __shfl_xor(v, j);
            int   oi = __shfl_xor(id, j);
            const bool lower    = ((lane & j) == 0);
            const bool mineBig  = (v > ov) || (v == ov && id < oi);
            const bool keepMine = (mineBig == lower);
            v  = keepMine ? v  : ov;
            id = keepMine ? id : oi;
        }
    }
}

__global__ void topk_replay(const float* __restrict__ s,
                            const float* __restrict__ qval,
                            const int* __restrict__ qidx,
                            float* __restrict__ out_scores,
                            float* __restrict__ out_idx, int k)
{
    const int lane = threadIdx.x;
    const int c = blockIdx.x;
    float val = qval[c * 64 + lane];
    int   idx = qidx[c * 64 + lane];
    const float sv = s[c * 64 + lane];

    for (int t = 0; t < 64; ++t) {
        const int i = c * 64 + t;
        const float si = __shfl(sv, t);
        if (lane < k) {
            const bool empty = (lane >= i);
            out_scores[(size_t)i * k + lane] = empty ? EMPTY_SENTINEL : (si + val);
            out_idx[(size_t)i * k + lane]    = (float)(empty ? lane : idx);
        }
        unsigned long long ge = __ballot(val >= si);
        int p = __popcll(ge);
        float upv = __shfl_up(val, 1);
        int   upi = __shfl_up(idx, 1);
        if (lane > p)       { val = upv; idx = upi; }
        else if (lane == p) { val = si;  idx = i;   }
    }
}

extern "C" void kernel_launch(void* const* d_in, const int* in_sizes, int n_in,
                              void* d_out, int out_size, void* d_ws, size_t ws_size,
                              hipStream_t stream)
{
    const float* mentions = (const float*)d_in[0];
    const float* W0   = (const float*)d_in[1];
    const float* b0   = (const float*)d_in[2];
    const float* W1   = (const float*)d_in[3];
    const float* b1   = (const float*)d_in[4];
    const float* Wout = (const float*)d_in[5];
    const float* bout = (const float*)d_in[6];

    const int D = 1536, H = 1536;
    const int M = in_sizes[0] / D;        // 8192
    const int k = out_size / (2 * M);     // 50
    const int NCH = M / 64;               // 128 chunks

    float* h0   = (float*)d_ws;
    float* h1   = h0 + (size_t)M * H;
    float* sc   = h1 + (size_t)M * H;
    float* cval = sc + M;
    int*   cidx = (int*)(cval + M);
    float* qval = (float*)(cidx + M);
    int*   qidx = (int*)(qval + M);

    dim3 g1(M / BM, H / BN);              // 64 x 12
    sgemm_bias_act<<<g1, 256, 0, stream>>>(mentions, W0, b0, h0, M, D, H);
    sgemm_bias_act<<<g1, 256, 0, stream>>>(h0, W1, b1, h1, M, H, H);
    gemv_wout<<<M / 4, 256, 0, stream>>>(h1, Wout, bout, sc, H);

    chunk_sort<<<NCH, 64, 0, stream>>>(sc, cval, cidx);
    prefix_merge<<<1, 64, 0, stream>>>(cval, cidx, qval, qidx, NCH);

    float* out_scores = (float*)d_out;
    float* out_idx    = (float*)d_out + (size_t)M * k;
    topk_replay<<<NCH, 64, 0, stream>>>(sc, qval, qidx, out_scores, out_idx, k);
}